// Round 1
// 696.604 us; speedup vs baseline: 1.0615x; 1.0615x over previous
//
#include <hip/hip_runtime.h>

// CTC loss forward, single wave per batch element: states in registers,
// neighbor exchange via one __shfl_up per step, NO barriers in the T-loop.
//
// R1 change vs previous version: the prefetch ring float rb[16]/r1[16]/r2[16]
// was demoted to SCRATCH (VGPR_Count=32 in rocprof -- 48 ring values cannot
// live in 32 VGPRs). Scratch reads share vmcnt with global loads and are
// issued right before use => s_waitcnt vmcnt(0) per step => every step paid
// a full HBM round trip (~1240 cy/step measured). Fix: NAMED SCALARS for the
// ring (macro-generated, fully hand-unrolled, zero runtime indexing), plus a
// one-step-pipelined shfl so ds_permute latency hides under the selects.
//
// Shapes fixed: B=128, T=1024, V=512, L=128, S=257.
constexpr int Tc = 1024;
constexpr int Vc = 512;
constexpr int Lc = 128;
constexpr int Sc = 2 * Lc + 1;     // 257
constexpr int BLANK = Vc - 1;      // 511
constexpr float NEGF = -1e30f;
constexpr float EPSF = 1e-7f;
constexpr int PF = 16;             // prefetch depth (3 loads/step -> 48 in flight)

__device__ __forceinline__ float lae2(float x, float y) {
    float m = fmaxf(x, y);
    return m + __logf(__expf(x - m) + __expf(y - m));
}
__device__ __forceinline__ float lae3(float x, float y, float z) {
    float m = fmaxf(fmaxf(x, y), z);
    return m + __logf(__expf(x - m) + __expf(y - m) + __expf(z - m));
}

__launch_bounds__(64, 1)
__global__ void ctc_fwd_wave(const int* __restrict__ labels,      // [B,L]
                             const int* __restrict__ label_len,   // [B,1]
                             const float* __restrict__ probs,     // [B,T,V]
                             const int* __restrict__ input_len,   // [B,1]
                             float* __restrict__ out)             // [B,1]
{
    const int b    = blockIdx.x;
    const int lane = threadIdx.x;          // lane L owns states 4L..4L+3; lane 63 also 256

    __shared__ float sa[Sc];

    // Labels for this lane's odd states: s=4L+1 -> label 2L, s=4L+3 -> label 2L+1
    const int lbase = b * Lc;
    const int l0  = labels[lbase + 2 * lane];
    const int l1  = labels[lbase + 2 * lane + 1];
    const int lm1 = (lane > 0) ? labels[lbase + 2 * lane - 1] : 0;
    const bool cs1 = (lane > 0) && (l0 != lm1);  // skip into state 4L+1
    const bool cs3 = (l1 != l0);                 // skip into state 4L+3
    const int len = input_len[b];

    const float* __restrict__ base = probs + (size_t)b * Tc * Vc;
    const float* __restrict__ pB = base + BLANK;
    const float* __restrict__ p1 = base + l0;
    const float* __restrict__ p2 = base + l1;

    // ---- named-scalar prefetch ring: NO arrays (arrays -> scratch -> vmcnt(0)/step) ----
#define RING16(X) X(0) X(1) X(2) X(3) X(4) X(5) X(6) X(7) \
                  X(8) X(9) X(10) X(11) X(12) X(13) X(14) X(15)
#define DECLR(j) float rb##j, r1##j, r2##j;
    RING16(DECLR)
#undef DECLR
#define INITR(j) { const size_t o = (size_t)(j) * Vc; \
                   rb##j = pB[o]; r1##j = p1[o]; r2##j = p2[o]; }
    RING16(INITR)
#undef INITR

    // alpha registers (time t-1 values)
    float a0 = (lane == 0) ? 0.0f : NEGF;   // state 4L
    float a1 = NEGF;                        // state 4L+1
    float a2 = NEGF;                        // state 4L+2
    float a3 = NEGF;                        // state 4L+3
    float a4 = NEGF;                        // state 256 (valid on lane 63)
    // prev-lane a3, pipelined one step ahead (shfl of initial a3 == NEGF)
    float u3 = NEGF;

    // One time-step on ring slot j. u3 holds shfl_up(a3_prev_step) already
    // masked for lane 0. At the end we issue shfl_up of the NEW a3 for the
    // next step; select-then-shfl == shfl-then-select since `live` is
    // uniform across the block, so this is bit-identical to the old code.
#define STEP(t, j, REFILL) { \
        const float lpb = __logf(rb##j + EPSF); \
        const float lp1 = __logf(r1##j + EPSF); \
        const float lp2 = __logf(r2##j + EPSF); \
        if (REFILL) { const size_t o = (size_t)((t) + PF) * Vc; \
            rb##j = pB[o]; r1##j = p1[o]; r2##j = p2[o]; } \
        const float n3 = lae3(a3, a2, cs3 ? a1 : NEGF) + lp2; \
        const float u3n = __shfl_up(n3, 1); \
        const float n0 = lae2(a0, u3) + lpb; \
        const float n1 = lae3(a1, a0, cs1 ? u3 : NEGF) + lp1; \
        const float n2 = lae2(a2, a1) + lpb; \
        const float n4 = lae2(a4, a3) + lpb; \
        const bool live = ((t) < len); \
        a0 = live ? n0 : a0; \
        a1 = live ? n1 : a1; \
        a2 = live ? n2 : a2; \
        a3 = live ? n3 : a3; \
        a4 = live ? n4 : a4; \
        u3 = live ? ((lane == 0) ? NEGF : u3n) : u3; \
    }

#define STEPS16(t0, R) \
        STEP((t0)+0,  0,  R) STEP((t0)+1,  1,  R) STEP((t0)+2,  2,  R) STEP((t0)+3,  3,  R) \
        STEP((t0)+4,  4,  R) STEP((t0)+5,  5,  R) STEP((t0)+6,  6,  R) STEP((t0)+7,  7,  R) \
        STEP((t0)+8,  8,  R) STEP((t0)+9,  9,  R) STEP((t0)+10, 10, R) STEP((t0)+11, 11, R) \
        STEP((t0)+12, 12, R) STEP((t0)+13, 13, R) STEP((t0)+14, 14, R) STEP((t0)+15, 15, R)

    for (int t0 = 0; t0 < Tc - PF; t0 += PF) {
        STEPS16(t0, 1)
    }
    STEPS16(Tc - PF, 0)

#undef STEP
#undef STEPS16
#undef RING16

    // Gather final alphas and emit loss
    sa[4 * lane + 0] = a0;
    sa[4 * lane + 1] = a1;
    sa[4 * lane + 2] = a2;
    sa[4 * lane + 3] = a3;
    if (lane == 63) sa[256] = a4;
    __syncthreads();
    if (lane == 0) {
        const int lab = label_len[b];
        const float x = sa[2 * lab];
        const float y = sa[2 * lab - 1];
        out[b] = -lae2(x, y);
    }
}

extern "C" void kernel_launch(void* const* d_in, const int* in_sizes, int n_in,
                              void* d_out, int out_size, void* d_ws, size_t ws_size,
                              hipStream_t stream) {
    const int*   labels    = (const int*)d_in[0];   // true_labels   [B,L]
    const int*   label_len = (const int*)d_in[1];   // true_lengths  [B,1]
    const float* probs     = (const float*)d_in[2]; // predicted_labels [B,T,V]
    const int*   input_len = (const int*)d_in[3];   // predicted_lengths [B,1]
    float*       out       = (float*)d_out;         // [B,1]

    const int B = in_sizes[1];
    ctc_fwd_wave<<<B, 64, 0, stream>>>(labels, label_len, probs, input_len, out);
}

// Round 2
// 668.909 us; speedup vs baseline: 1.1055x; 1.0414x over previous
//
#include <hip/hip_runtime.h>

// CTC loss forward, single wave per batch element: states in registers,
// neighbor exchange via one __shfl_up per step, NO barriers in the T-loop.
//
// R2 change: R1's named-scalar ring still ran at ~1030 cy/step with
// VGPR_Count=36 -- the compiler's register-pressure scheduler SANK each
// global load to just before its use (effective prefetch depth 1, one
// memory round trip per step). Fix per the AITER pattern: issue ring loads
// via asm volatile global_load_dword (volatile asm order is preserved) and
// gate consumption with hand-counted s_waitcnt vmcnt(N) (45 in steady
// state, never 0). The waitcnt asm ties the ring registers as "+v"
// operands so consumers are dataflow-ordered after the wait (rule #18).
//
// Shapes fixed: B=128, T=1024, V=512, L=128, S=257.
constexpr int Tc = 1024;
constexpr int Vc = 512;
constexpr int Lc = 128;
constexpr int Sc = 2 * Lc + 1;     // 257
constexpr int BLANK = Vc - 1;      // 511
constexpr float NEGF = -1e30f;
constexpr float EPSF = 1e-7f;
constexpr int PF = 16;             // prefetch depth (3 loads/step -> 48 in flight)

__device__ __forceinline__ float lae2(float x, float y) {
    float m = fmaxf(x, y);
    return m + __logf(__expf(x - m) + __expf(y - m));
}
__device__ __forceinline__ float lae3(float x, float y, float z) {
    float m = fmaxf(fmaxf(x, y), z);
    return m + __logf(__expf(x - m) + __expf(y - m) + __expf(z - m));
}

__launch_bounds__(64, 1)
__global__ void ctc_fwd_wave(const int* __restrict__ labels,      // [B,L]
                             const int* __restrict__ label_len,   // [B,1]
                             const float* __restrict__ probs,     // [B,T,V]
                             const int* __restrict__ input_len,   // [B,1]
                             float* __restrict__ out)             // [B,1]
{
    const int b    = blockIdx.x;
    const int lane = threadIdx.x;          // lane L owns states 4L..4L+3; lane 63 also 256

    __shared__ float sa[Sc];

    // Labels for this lane's odd states: s=4L+1 -> label 2L, s=4L+3 -> label 2L+1
    const int lbase = b * Lc;
    const int l0  = labels[lbase + 2 * lane];
    const int l1  = labels[lbase + 2 * lane + 1];
    const int lm1 = (lane > 0) ? labels[lbase + 2 * lane - 1] : 0;
    const bool cs1 = (lane > 0) && (l0 != lm1);  // skip into state 4L+1
    const bool cs3 = (l1 != l0);                 // skip into state 4L+3
    const int len = input_len[b];

    // Uniform SGPR base for this batch row-block; per-lane 32-bit byte offsets.
    const float* __restrict__ srow = probs + (size_t)b * Tc * Vc;
    unsigned oB = (unsigned)(BLANK * 4);   // blank column (lane-uniform)
    unsigned o1 = (unsigned)(l0 * 4);      // label 2*lane column
    unsigned o2 = (unsigned)(l1 * 4);      // label 2*lane+1 column

#define RING16(X) X(0) X(1) X(2) X(3) X(4) X(5) X(6) X(7) \
                  X(8) X(9) X(10) X(11) X(12) X(13) X(14) X(15)
#define DECLR(j) float rb##j, r1##j, r2##j;
    RING16(DECLR)
#undef DECLR

    // Load issue is pinned by asm volatile (cannot be sunk by the scheduler).
    // SADDR form: addr = SGPR64 base + zext(VGPR32 offset).
#define GLOAD(dst, off) \
    asm volatile("global_load_dword %0, %1, %2" : "=v"(dst) : "v"(off), "s"(srow))

    // Prime the ring: slot j holds row t=j. 48 loads in flight.
#define INITR(j) GLOAD(rb##j, oB + (unsigned)((j) * Vc * 4)); \
                 GLOAD(r1##j, o1 + (unsigned)((j) * Vc * 4)); \
                 GLOAD(r2##j, o2 + (unsigned)((j) * Vc * 4));
    RING16(INITR)
#undef INITR

    // Offsets now point at the next row to prefetch (t = PF).
    oB += (unsigned)(PF * Vc * 4);
    o1 += (unsigned)(PF * Vc * 4);
    o2 += (unsigned)(PF * Vc * 4);

    // alpha registers (time t-1 values)
    float a0 = (lane == 0) ? 0.0f : NEGF;   // state 4L
    float a1 = NEGF;                        // state 4L+1
    float a2 = NEGF;                        // state 4L+2
    float a3 = NEGF;                        // state 4L+3
    float a4 = NEGF;                        // state 256 (valid on lane 63)
    float u3 = NEGF;                        // prev-lane a3, pipelined one step

    // Counted wait: vmcnt retires in issue order, so outstanding<=N proves the
    // 3 oldest loads (slot j's) have landed. Ties the ring regs so the
    // consumers below are dataflow-ordered after this wait.
#define WAITR(N, j) \
    asm volatile("s_waitcnt vmcnt(" #N ")" : "+v"(rb##j), "+v"(r1##j), "+v"(r2##j))

#define STEP(t, j, N, REFILL) { \
        WAITR(N, j); \
        const float lpb = __logf(rb##j + EPSF); \
        const float lp1 = __logf(r1##j + EPSF); \
        const float lp2 = __logf(r2##j + EPSF); \
        if (REFILL) { \
            GLOAD(rb##j, oB); GLOAD(r1##j, o1); GLOAD(r2##j, o2); \
            oB += (unsigned)(Vc * 4); \
            o1 += (unsigned)(Vc * 4); \
            o2 += (unsigned)(Vc * 4); \
        } \
        const float n3 = lae3(a3, a2, cs3 ? a1 : NEGF) + lp2; \
        const float u3n = __shfl_up(n3, 1); \
        const float n0 = lae2(a0, u3) + lpb; \
        const float n1 = lae3(a1, a0, cs1 ? u3 : NEGF) + lp1; \
        const float n2 = lae2(a2, a1) + lpb; \
        const float n4 = lae2(a4, a3) + lpb; \
        const bool live = ((t) < len); \
        a0 = live ? n0 : a0; \
        a1 = live ? n1 : a1; \
        a2 = live ? n2 : a2; \
        a3 = live ? n3 : a3; \
        a4 = live ? n4 : a4; \
        u3 = live ? ((lane == 0) ? NEGF : u3n) : u3; \
    }

    // Steady state: 48 in flight; each step waits vmcnt(45), consumes slot j,
    // issues 3 refills for row t+PF.
    for (int t0 = 0; t0 < Tc - PF; t0 += PF) {
        STEP(t0+0,  0,  45, 1) STEP(t0+1,  1,  45, 1) STEP(t0+2,  2,  45, 1) STEP(t0+3,  3,  45, 1)
        STEP(t0+4,  4,  45, 1) STEP(t0+5,  5,  45, 1) STEP(t0+6,  6,  45, 1) STEP(t0+7,  7,  45, 1)
        STEP(t0+8,  8,  45, 1) STEP(t0+9,  9,  45, 1) STEP(t0+10, 10, 45, 1) STEP(t0+11, 11, 45, 1)
        STEP(t0+12, 12, 45, 1) STEP(t0+13, 13, 45, 1) STEP(t0+14, 14, 45, 1) STEP(t0+15, 15, 45, 1)
    }
    // Drain: no refills; outstanding shrinks by 3 per step.
    {
        constexpr int tF = Tc - PF;
        STEP(tF+0,  0,  45, 0) STEP(tF+1,  1,  42, 0) STEP(tF+2,  2,  39, 0) STEP(tF+3,  3,  36, 0)
        STEP(tF+4,  4,  33, 0) STEP(tF+5,  5,  30, 0) STEP(tF+6,  6,  27, 0) STEP(tF+7,  7,  24, 0)
        STEP(tF+8,  8,  21, 0) STEP(tF+9,  9,  18, 0) STEP(tF+10, 10, 15, 0) STEP(tF+11, 11, 12, 0)
        STEP(tF+12, 12, 9,  0) STEP(tF+13, 13, 6,  0) STEP(tF+14, 14, 3,  0) STEP(tF+15, 15, 0,  0)
    }

#undef STEP
#undef WAITR
#undef GLOAD
#undef RING16

    // Gather final alphas and emit loss
    sa[4 * lane + 0] = a0;
    sa[4 * lane + 1] = a1;
    sa[4 * lane + 2] = a2;
    sa[4 * lane + 3] = a3;
    if (lane == 63) sa[256] = a4;
    __syncthreads();
    if (lane == 0) {
        const int lab = label_len[b];
        const float x = sa[2 * lab];
        const float y = sa[2 * lab - 1];
        out[b] = -lae2(x, y);
    }
}

extern "C" void kernel_launch(void* const* d_in, const int* in_sizes, int n_in,
                              void* d_out, int out_size, void* d_ws, size_t ws_size,
                              hipStream_t stream) {
    const int*   labels    = (const int*)d_in[0];   // true_labels   [B,L]
    const int*   label_len = (const int*)d_in[1];   // true_lengths  [B,1]
    const float* probs     = (const float*)d_in[2]; // predicted_labels [B,T,V]
    const int*   input_len = (const int*)d_in[3];   // predicted_lengths [B,1]
    float*       out       = (float*)d_out;         // [B,1]

    const int B = in_sizes[1];
    ctc_fwd_wave<<<B, 64, 0, stream>>>(labels, label_len, probs, input_len, out);
}

// Round 3
// 662.574 us; speedup vs baseline: 1.1160x; 1.0096x over previous
//
#include <hip/hip_runtime.h>

// CTC loss forward, single wave per batch element.
//
// R3 change: R2's counted-vmcnt scattered loads still ran ~970 cy/step.
// Root cause: 3 scattered wave-loads/step (random label columns) = ~30
// distinct cachelines each; 48 in-flight wave-loads want ~1400 outstanding
// line-misses vs ~100-150/CU the HW can track -> effective prefetch depth
// ~1 step -> one HBM round trip per step. Fix: fetch the ENTIRE 2KB row
// coalesced via 2x global_load_lds_dwordx4 into a 16-row LDS ring (the
// needed columns touch ~30/32 lines anyway), then each lane ds_reads its 3
// columns from LDS, prefetched one step ahead. Counted vmcnt(28) /
// lgkmcnt(3), never 0, no barriers in the T-loop (single wave => no
// __syncthreads needed for LDS coherence).
//
// Shapes fixed: B=128, T=1024, V=512, L=128, S=257.
constexpr int Tc = 1024;
constexpr int Vc = 512;
constexpr int Lc = 128;
constexpr int Sc = 2 * Lc + 1;     // 257
constexpr int BLANK = Vc - 1;      // 511
constexpr float NEGF = -1e30f;
constexpr float EPSF = 1e-7f;
constexpr int RING = 16;           // LDS row ring (2 VMEM ops/row -> 32 in flight)

__device__ __forceinline__ float lae2(float x, float y) {
    float m = fmaxf(x, y);
    return m + __logf(__expf(x - m) + __expf(y - m));
}
__device__ __forceinline__ float lae3(float x, float y, float z) {
    float m = fmaxf(fmaxf(x, y), z);
    return m + __logf(__expf(x - m) + __expf(y - m) + __expf(z - m));
}

__launch_bounds__(64, 1)
__global__ void ctc_fwd_wave(const int* __restrict__ labels,      // [B,L]
                             const int* __restrict__ label_len,   // [B,1]
                             const float* __restrict__ probs,     // [B,T,V]
                             const int* __restrict__ input_len,   // [B,1]
                             float* __restrict__ out)             // [B,1]
{
    const int b    = blockIdx.x;
    const int lane = threadIdx.x;          // lane L owns states 4L..4L+3; lane 63 also 256

    __shared__ float rows[RING][Vc];       // 32 KB row ring
    __shared__ float sa[Sc];

    // Labels for this lane's odd states: s=4L+1 -> label 2L, s=4L+3 -> label 2L+1
    const int lbase = b * Lc;
    const int l0  = labels[lbase + 2 * lane];
    const int l1  = labels[lbase + 2 * lane + 1];
    const int lm1 = (lane > 0) ? labels[lbase + 2 * lane - 1] : 0;
    const bool cs1 = (lane > 0) && (l0 != lm1);  // skip into state 4L+1
    const bool cs3 = (l1 != l0);                 // skip into state 4L+3
    const int len = input_len[b];

    const float* __restrict__ srow = probs + (size_t)b * Tc * Vc;
    const float* __restrict__ gl   = srow + lane * 4;   // per-lane 16B chunk base

    // LDS byte offsets (low 32 bits of a generic LDS address == LDS offset).
    const unsigned ldsRows = (unsigned)(size_t)&rows[0][0];
    const unsigned cB = ldsRows + (unsigned)(BLANK * 4);  // lane-uniform -> broadcast
    const unsigned c1 = ldsRows + (unsigned)l0 * 4u;
    const unsigned c2 = ldsRows + (unsigned)l1 * 4u;

    // Force every compiler-issued load to be live BEFORE the clean-slate wait,
    // so the in-loop vmcnt/lgkmcnt streams contain ONLY our asm/builtin ops.
    asm volatile("" :: "v"(lm1), "v"(len));
    asm volatile("s_waitcnt vmcnt(0) lgkmcnt(0)" ::: "memory");

    // Coalesced row DMA: 2x global_load_lds dwordx4. LDS dest is wave-uniform
    // base + lane*16 (linear row layout, exactly rows[slot][.]).
#define DMA_ROW(slot, trow) do { \
        const float* gp_ = gl + (size_t)(trow) * Vc; \
        __builtin_amdgcn_global_load_lds( \
            (const __attribute__((address_space(1))) void*)(size_t)gp_, \
            (__attribute__((address_space(3))) void*)(size_t)(ldsRows + (unsigned)((slot) * (Vc * 4))), \
            16, 0, 0); \
        __builtin_amdgcn_global_load_lds( \
            (const __attribute__((address_space(1))) void*)(size_t)(gp_ + 256), \
            (__attribute__((address_space(3))) void*)(size_t)(ldsRows + (unsigned)((slot) * (Vc * 4) + 1024)), \
            16, 0, 0); \
    } while (0)

#define DSREAD(dst, addr) asm volatile("ds_read_b32 %0, %1" : "=v"(dst) : "v"(addr))
#define WAIT_VM(N)  asm volatile("s_waitcnt vmcnt(" #N ")" ::: "memory")
#define WAIT_LGKM3(x, y, z) \
    asm volatile("s_waitcnt lgkmcnt(3)" : "+v"(x), "+v"(y), "+v"(z) :: "memory")
#define WAIT_LGKM0(x, y, z) \
    asm volatile("s_waitcnt lgkmcnt(0)" : "+v"(x), "+v"(y), "+v"(z) :: "memory")

    // Prime the ring: rows 0..15 -> 32 VMEM ops in flight.
    DMA_ROW(0, 0)  ; DMA_ROW(1, 1)  ; DMA_ROW(2, 2)  ; DMA_ROW(3, 3)  ;
    DMA_ROW(4, 4)  ; DMA_ROW(5, 5)  ; DMA_ROW(6, 6)  ; DMA_ROW(7, 7)  ;
    DMA_ROW(8, 8)  ; DMA_ROW(9, 9)  ; DMA_ROW(10, 10); DMA_ROW(11, 11);
    DMA_ROW(12, 12); DMA_ROW(13, 13); DMA_ROW(14, 14); DMA_ROW(15, 15);

    // alpha registers (time t-1 values)
    float a0 = (lane == 0) ? 0.0f : NEGF;   // state 4L
    float a1 = NEGF;                        // state 4L+1
    float a2 = NEGF;                        // state 4L+2
    float a3 = NEGF;                        // state 4L+3
    float a4 = NEGF;                        // state 256 (valid on lane 63)
    float u3 = NEGF;                        // prev-lane a3, pipelined one step

    // LDS->reg double-buffer regs (A = even t, B = odd t)
    float fAb, fA1, fA2, fBb, fB1, fB2;

    // Preload row 0 column regs (set A).
    WAIT_VM(30);                      // row 0 landed in LDS
    DSREAD(fAb, cB); DSREAD(fA1, c1); DSREAD(fA2, c2);

    // One step: [A] counted vmcnt (row t+1 in LDS)  [B] ds_read row t+1 -> NXT
    // [C] lgkm wait ties CUR (row t regs ready)      [D] refill slot j <- row t+RING
    // [E] recurrence update (bit-identical math to previous rounds).
#define STEP(t_, j, NV, DOB, DOD, CB_, C1_, C2_, NB_, N1_, N2_, LG) { \
        WAIT_VM(NV); \
        if (DOB) { \
            const unsigned sl_ = (unsigned)((((j) + 1) & (RING - 1)) * (Vc * 4)); \
            unsigned ab_ = cB + sl_, ax_ = c1 + sl_, ay_ = c2 + sl_; \
            DSREAD(NB_, ab_); DSREAD(N1_, ax_); DSREAD(N2_, ay_); \
        } \
        LG(CB_, C1_, C2_); \
        __builtin_amdgcn_sched_barrier(0); \
        if (DOD) DMA_ROW((j), (t_) + RING); \
        const float lpb = __logf(CB_ + EPSF); \
        const float lp1 = __logf(C1_ + EPSF); \
        const float lp2 = __logf(C2_ + EPSF); \
        const float n3 = lae3(a3, a2, cs3 ? a1 : NEGF) + lp2; \
        const float u3n = __shfl_up(n3, 1); \
        const float n0 = lae2(a0, u3) + lpb; \
        const float n1 = lae3(a1, a0, cs1 ? u3 : NEGF) + lp1; \
        const float n2 = lae2(a2, a1) + lpb; \
        const float n4 = lae2(a4, a3) + lpb; \
        const bool live = ((t_) < len); \
        a0 = live ? n0 : a0; \
        a1 = live ? n1 : a1; \
        a2 = live ? n2 : a2; \
        a3 = live ? n3 : a3; \
        a4 = live ? n4 : a4; \
        u3 = live ? ((lane == 0) ? NEGF : u3n) : u3; \
    }

    // Steady state: t = 0..1007. Each step: wait vmcnt(28) (retire row t+2's
    // pair is NOT required -- 28 proves rows <= t+1 are resident), prefetch
    // ds_reads for row t+1, consume row t, refill slot j with row t+16.
    for (int t0 = 0; t0 < Tc - RING; t0 += 16) {
        STEP(t0 + 0,  0,  28, 1, 1, fAb, fA1, fA2, fBb, fB1, fB2, WAIT_LGKM3)
        STEP(t0 + 1,  1,  28, 1, 1, fBb, fB1, fB2, fAb, fA1, fA2, WAIT_LGKM3)
        STEP(t0 + 2,  2,  28, 1, 1, fAb, fA1, fA2, fBb, fB1, fB2, WAIT_LGKM3)
        STEP(t0 + 3,  3,  28, 1, 1, fBb, fB1, fB2, fAb, fA1, fA2, WAIT_LGKM3)
        STEP(t0 + 4,  4,  28, 1, 1, fAb, fA1, fA2, fBb, fB1, fB2, WAIT_LGKM3)
        STEP(t0 + 5,  5,  28, 1, 1, fBb, fB1, fB2, fAb, fA1, fA2, WAIT_LGKM3)
        STEP(t0 + 6,  6,  28, 1, 1, fAb, fA1, fA2, fBb, fB1, fB2, WAIT_LGKM3)
        STEP(t0 + 7,  7,  28, 1, 1, fBb, fB1, fB2, fAb, fA1, fA2, WAIT_LGKM3)
        STEP(t0 + 8,  8,  28, 1, 1, fAb, fA1, fA2, fBb, fB1, fB2, WAIT_LGKM3)
        STEP(t0 + 9,  9,  28, 1, 1, fBb, fB1, fB2, fAb, fA1, fA2, WAIT_LGKM3)
        STEP(t0 + 10, 10, 28, 1, 1, fAb, fA1, fA2, fBb, fB1, fB2, WAIT_LGKM3)
        STEP(t0 + 11, 11, 28, 1, 1, fBb, fB1, fB2, fAb, fA1, fA2, WAIT_LGKM3)
        STEP(t0 + 12, 12, 28, 1, 1, fAb, fA1, fA2, fBb, fB1, fB2, WAIT_LGKM3)
        STEP(t0 + 13, 13, 28, 1, 1, fBb, fB1, fB2, fAb, fA1, fA2, WAIT_LGKM3)
        STEP(t0 + 14, 14, 28, 1, 1, fAb, fA1, fA2, fBb, fB1, fB2, WAIT_LGKM3)
        STEP(t0 + 15, 15, 28, 1, 1, fBb, fB1, fB2, fAb, fA1, fA2, WAIT_LGKM3)
    }
    // Drain: t = 1008..1023, no refills, counted drain (never a premature 0).
    STEP(1008, 0,  26, 1, 0, fAb, fA1, fA2, fBb, fB1, fB2, WAIT_LGKM3)
    STEP(1009, 1,  24, 1, 0, fBb, fB1, fB2, fAb, fA1, fA2, WAIT_LGKM3)
    STEP(1010, 2,  22, 1, 0, fAb, fA1, fA2, fBb, fB1, fB2, WAIT_LGKM3)
    STEP(1011, 3,  20, 1, 0, fBb, fB1, fB2, fAb, fA1, fA2, WAIT_LGKM3)
    STEP(1012, 4,  18, 1, 0, fAb, fA1, fA2, fBb, fB1, fB2, WAIT_LGKM3)
    STEP(1013, 5,  16, 1, 0, fBb, fB1, fB2, fAb, fA1, fA2, WAIT_LGKM3)
    STEP(1014, 6,  14, 1, 0, fAb, fA1, fA2, fBb, fB1, fB2, WAIT_LGKM3)
    STEP(1015, 7,  12, 1, 0, fBb, fB1, fB2, fAb, fA1, fA2, WAIT_LGKM3)
    STEP(1016, 8,  10, 1, 0, fAb, fA1, fA2, fBb, fB1, fB2, WAIT_LGKM3)
    STEP(1017, 9,  8,  1, 0, fBb, fB1, fB2, fAb, fA1, fA2, WAIT_LGKM3)
    STEP(1018, 10, 6,  1, 0, fAb, fA1, fA2, fBb, fB1, fB2, WAIT_LGKM3)
    STEP(1019, 11, 4,  1, 0, fBb, fB1, fB2, fAb, fA1, fA2, WAIT_LGKM3)
    STEP(1020, 12, 2,  1, 0, fAb, fA1, fA2, fBb, fB1, fB2, WAIT_LGKM3)
    STEP(1021, 13, 0,  1, 0, fBb, fB1, fB2, fAb, fA1, fA2, WAIT_LGKM3)
    STEP(1022, 14, 0,  1, 0, fAb, fA1, fA2, fBb, fB1, fB2, WAIT_LGKM3)
    STEP(1023, 15, 0,  0, 0, fBb, fB1, fB2, fAb, fA1, fA2, WAIT_LGKM0)

#undef STEP
#undef WAIT_LGKM0
#undef WAIT_LGKM3
#undef WAIT_VM
#undef DSREAD
#undef DMA_ROW

    // Gather final alphas and emit loss
    sa[4 * lane + 0] = a0;
    sa[4 * lane + 1] = a1;
    sa[4 * lane + 2] = a2;
    sa[4 * lane + 3] = a3;
    if (lane == 63) sa[256] = a4;
    __syncthreads();
    if (lane == 0) {
        const int lab = label_len[b];
        const float x = sa[2 * lab];
        const float y = sa[2 * lab - 1];
        out[b] = -lae2(x, y);
    }
}

extern "C" void kernel_launch(void* const* d_in, const int* in_sizes, int n_in,
                              void* d_out, int out_size, void* d_ws, size_t ws_size,
                              hipStream_t stream) {
    const int*   labels    = (const int*)d_in[0];   // true_labels   [B,L]
    const int*   label_len = (const int*)d_in[1];   // true_lengths  [B,1]
    const float* probs     = (const float*)d_in[2]; // predicted_labels [B,T,V]
    const int*   input_len = (const int*)d_in[3];   // predicted_lengths [B,1]
    float*       out       = (float*)d_out;         // [B,1]

    const int B = in_sizes[1];
    ctc_fwd_wave<<<B, 64, 0, stream>>>(labels, label_len, probs, input_len, out);
}

// Round 6
// 656.031 us; speedup vs baseline: 1.1272x; 1.0100x over previous
//
#include <hip/hip_runtime.h>

// CTC loss forward, single wave per batch element (R6 = R3 minus asm ds_reads).
//
// R4/R5 (two-kernel + workspace) crashed twice with no diagnostics -> that
// structure is abandoned; back to the R3 skeleton (single launch, passing).
//
// Unified R1-R3 post-mortem: every variant ran ~1 HBM latency (~950 cy) per
// step because something forced an effective vmcnt(0) each step:
//   R1: compiler sank the loads (depth 1).
//   R2: ring spilled to scratch (VGPR=36); spill-store waits its own load.
//   R3: inline-asm ds_reads -- the waitcnt pass treats asm volatile as an
//       unknown memory access that may read LDS written by outstanding
//       global_load_lds -> conservative vmcnt(0) before EACH asm ds_read,
//       which drains the refill DMA issued one step earlier.
// Discriminator: m201/m218 (8-phase GEMM) = asm counted waitcnt + COMPILER
// ds_reads + global_load_lds, and loads stay in flight. So R6 keeps R3's
// DMA ring + counted asm vmcnt ("memory" clobber) but does the LDS reads in
// plain C++ (compile-time slot -> ds_read with imm offset; compiler inserts
// only fine-grained lgkmcnt and no vmcnt before its own ds_reads). The
// per-step "memory" clobber also keeps rows[] reads honest (the array is
// only written via the DMA builtin).
//
// Shapes fixed: B=128, T=1024, V=512, L=128, S=257.
constexpr int Tc = 1024;
constexpr int Vc = 512;
constexpr int Lc = 128;
constexpr int Sc = 2 * Lc + 1;     // 257
constexpr int BLANK = Vc - 1;      // 511
constexpr float NEGF = -1e30f;
constexpr float EPSF = 1e-7f;
constexpr int RING = 16;           // LDS row ring (2 DMA ops/row -> 32 in flight)

__device__ __forceinline__ float lae2(float x, float y) {
    float m = fmaxf(x, y);
    return m + __logf(__expf(x - m) + __expf(y - m));
}
__device__ __forceinline__ float lae3(float x, float y, float z) {
    float m = fmaxf(fmaxf(x, y), z);
    return m + __logf(__expf(x - m) + __expf(y - m) + __expf(z - m));
}

__launch_bounds__(64, 1)
__global__ void ctc_fwd_wave(const int* __restrict__ labels,      // [B,L]
                             const int* __restrict__ label_len,   // [B,1]
                             const float* __restrict__ probs,     // [B,T,V]
                             const int* __restrict__ input_len,   // [B,1]
                             float* __restrict__ out)             // [B,1]
{
    const int b    = blockIdx.x;
    const int lane = threadIdx.x;          // lane L owns states 4L..4L+3; lane 63 also 256

    __shared__ float rows[RING][Vc];       // 32 KB row ring
    __shared__ float sa[Sc];

    // Labels for this lane's odd states: s=4L+1 -> label 2L, s=4L+3 -> label 2L+1
    const int lbase = b * Lc;
    const int l0  = labels[lbase + 2 * lane];
    const int l1  = labels[lbase + 2 * lane + 1];
    const int lm1 = (lane > 0) ? labels[lbase + 2 * lane - 1] : 0;
    const bool cs1 = (lane > 0) && (l0 != lm1);  // skip into state 4L+1
    const bool cs3 = (l1 != l0);                 // skip into state 4L+3
    const int len = input_len[b];

    const float* __restrict__ srow = probs + (size_t)b * Tc * Vc;
    const float* __restrict__ gl   = srow + lane * 4;   // per-lane 16B chunk base

    // Wave-uniform LDS byte base for the DMA destination (R3-proven pattern).
    const unsigned ldsRows = (unsigned)(size_t)&rows[0][0];

    // LDS read pointers: base VGPR carries the column; compile-time slot
    // index becomes the ds_read immediate offset (slot*2048 <= 30720 < 64K).
    const float* __restrict__ rBp = &rows[0][BLANK];   // lane-uniform -> broadcast
    const float* __restrict__ r1p = &rows[0][l0];
    const float* __restrict__ r2p = &rows[0][l1];

    // Clean slate: compiler-issued prelude loads retire before the counted stream.
    asm volatile("" :: "v"(lm1), "v"(len));
    asm volatile("s_waitcnt vmcnt(0) lgkmcnt(0)" ::: "memory");

    // Coalesced row DMA: 2x global_load_lds dwordx4 (wave-uniform LDS base +
    // lane*16 = linear rows[slot][.]).
#define DMA_ROW(slot, trow) do { \
        const float* gp_ = gl + (size_t)(trow) * Vc; \
        __builtin_amdgcn_global_load_lds( \
            (const __attribute__((address_space(1))) void*)(size_t)gp_, \
            (__attribute__((address_space(3))) void*)(size_t)(ldsRows + (unsigned)((slot) * (Vc * 4))), \
            16, 0, 0); \
        __builtin_amdgcn_global_load_lds( \
            (const __attribute__((address_space(1))) void*)(size_t)(gp_ + 256), \
            (__attribute__((address_space(3))) void*)(size_t)(ldsRows + (unsigned)((slot) * (Vc * 4) + 1024)), \
            16, 0, 0); \
    } while (0)

    // Counted wait, never 0 in steady state. "memory" clobber: C++ LDS reads
    // cannot be hoisted above it, and rows[] values are re-read after it.
#define WAIT_VM(N)  asm volatile("s_waitcnt vmcnt(" #N ")" ::: "memory")

    // Prime the ring: rows 0..15 -> 32 DMA ops in flight.
    DMA_ROW(0, 0)  ; DMA_ROW(1, 1)  ; DMA_ROW(2, 2)  ; DMA_ROW(3, 3)  ;
    DMA_ROW(4, 4)  ; DMA_ROW(5, 5)  ; DMA_ROW(6, 6)  ; DMA_ROW(7, 7)  ;
    DMA_ROW(8, 8)  ; DMA_ROW(9, 9)  ; DMA_ROW(10, 10); DMA_ROW(11, 11);
    DMA_ROW(12, 12); DMA_ROW(13, 13); DMA_ROW(14, 14); DMA_ROW(15, 15);

    // alpha registers (time t-1 values)
    float a0 = (lane == 0) ? 0.0f : NEGF;   // state 4L
    float a1 = NEGF;                        // state 4L+1
    float a2 = NEGF;                        // state 4L+2
    float a3 = NEGF;                        // state 4L+3
    float a4 = NEGF;                        // state 256 (valid on lane 63)
    float u3 = NEGF;                        // prev-lane a3, pipelined one step

    // LDS->reg double-buffer regs (A = even t, B = odd t)
    float fAb, fA1, fA2, fBb, fB1, fB2;

    // Preload row 0 column regs (set A).
    WAIT_VM(30);                      // row 0 landed in LDS
    fAb = rBp[0]; fA1 = r1p[0]; fA2 = r2p[0];

    // One step: [A] counted vmcnt (row t+1 resident)  [B] C++ ds_read row t+1
    // -> NXT regs (compiler lgkmcnt)  [C] refill slot j <- row t+RING
    // [D] recurrence on CUR regs (math identical to R1-R5 -> absmax 0).
#define STEP(t_, j, NV, DOB, DOD, CB_, C1_, C2_, NB_, N1_, N2_) { \
        WAIT_VM(NV); \
        if (DOB) { \
            const int s_ = (((j) + 1) & (RING - 1)) * Vc; \
            NB_ = rBp[s_]; N1_ = r1p[s_]; N2_ = r2p[s_]; \
        } \
        if (DOD) DMA_ROW((j), (t_) + RING); \
        const float lpb = __logf(CB_ + EPSF); \
        const float lp1 = __logf(C1_ + EPSF); \
        const float lp2 = __logf(C2_ + EPSF); \
        const float n3 = lae3(a3, a2, cs3 ? a1 : NEGF) + lp2; \
        const float u3n = __shfl_up(n3, 1); \
        const float n0 = lae2(a0, u3) + lpb; \
        const float n1 = lae3(a1, a0, cs1 ? u3 : NEGF) + lp1; \
        const float n2 = lae2(a2, a1) + lpb; \
        const float n4 = lae2(a4, a3) + lpb; \
        const bool live = ((t_) < len); \
        a0 = live ? n0 : a0; \
        a1 = live ? n1 : a1; \
        a2 = live ? n2 : a2; \
        a3 = live ? n3 : a3; \
        a4 = live ? n4 : a4; \
        u3 = live ? ((lane == 0) ? NEGF : u3n) : u3; \
    }

    // Steady state: wait vmcnt(28) (rows <= t+1 resident), prefetch ds_reads
    // for row t+1, refill slot j with row t+16, compute row t.
    for (int t0 = 0; t0 < Tc - RING; t0 += 16) {
        STEP(t0 + 0,  0,  28, 1, 1, fAb, fA1, fA2, fBb, fB1, fB2)
        STEP(t0 + 1,  1,  28, 1, 1, fBb, fB1, fB2, fAb, fA1, fA2)
        STEP(t0 + 2,  2,  28, 1, 1, fAb, fA1, fA2, fBb, fB1, fB2)
        STEP(t0 + 3,  3,  28, 1, 1, fBb, fB1, fB2, fAb, fA1, fA2)
        STEP(t0 + 4,  4,  28, 1, 1, fAb, fA1, fA2, fBb, fB1, fB2)
        STEP(t0 + 5,  5,  28, 1, 1, fBb, fB1, fB2, fAb, fA1, fA2)
        STEP(t0 + 6,  6,  28, 1, 1, fAb, fA1, fA2, fBb, fB1, fB2)
        STEP(t0 + 7,  7,  28, 1, 1, fBb, fB1, fB2, fAb, fA1, fA2)
        STEP(t0 + 8,  8,  28, 1, 1, fAb, fA1, fA2, fBb, fB1, fB2)
        STEP(t0 + 9,  9,  28, 1, 1, fBb, fB1, fB2, fAb, fA1, fA2)
        STEP(t0 + 10, 10, 28, 1, 1, fAb, fA1, fA2, fBb, fB1, fB2)
        STEP(t0 + 11, 11, 28, 1, 1, fBb, fB1, fB2, fAb, fA1, fA2)
        STEP(t0 + 12, 12, 28, 1, 1, fAb, fA1, fA2, fBb, fB1, fB2)
        STEP(t0 + 13, 13, 28, 1, 1, fBb, fB1, fB2, fAb, fA1, fA2)
        STEP(t0 + 14, 14, 28, 1, 1, fAb, fA1, fA2, fBb, fB1, fB2)
        STEP(t0 + 15, 15, 28, 1, 1, fBb, fB1, fB2, fAb, fA1, fA2)
    }
    // Drain: t = 1008..1023, no refills, counted drain (never a premature 0).
    STEP(1008, 0,  26, 1, 0, fAb, fA1, fA2, fBb, fB1, fB2)
    STEP(1009, 1,  24, 1, 0, fBb, fB1, fB2, fAb, fA1, fA2)
    STEP(1010, 2,  22, 1, 0, fAb, fA1, fA2, fBb, fB1, fB2)
    STEP(1011, 3,  20, 1, 0, fBb, fB1, fB2, fAb, fA1, fA2)
    STEP(1012, 4,  18, 1, 0, fAb, fA1, fA2, fBb, fB1, fB2)
    STEP(1013, 5,  16, 1, 0, fBb, fB1, fB2, fAb, fA1, fA2)
    STEP(1014, 6,  14, 1, 0, fAb, fA1, fA2, fBb, fB1, fB2)
    STEP(1015, 7,  12, 1, 0, fBb, fB1, fB2, fAb, fA1, fA2)
    STEP(1016, 8,  10, 1, 0, fAb, fA1, fA2, fBb, fB1, fB2)
    STEP(1017, 9,  8,  1, 0, fBb, fB1, fB2, fAb, fA1, fA2)
    STEP(1018, 10, 6,  1, 0, fAb, fA1, fA2, fBb, fB1, fB2)
    STEP(1019, 11, 4,  1, 0, fBb, fB1, fB2, fAb, fA1, fA2)
    STEP(1020, 12, 2,  1, 0, fAb, fA1, fA2, fBb, fB1, fB2)
    STEP(1021, 13, 0,  1, 0, fBb, fB1, fB2, fAb, fA1, fA2)
    STEP(1022, 14, 0,  1, 0, fAb, fA1, fA2, fBb, fB1, fB2)
    STEP(1023, 15, 0,  0, 0, fBb, fB1, fB2, fAb, fA1, fA2)

#undef STEP
#undef WAIT_VM
#undef DMA_ROW

    // Gather final alphas and emit loss
    sa[4 * lane + 0] = a0;
    sa[4 * lane + 1] = a1;
    sa[4 * lane + 2] = a2;
    sa[4 * lane + 3] = a3;
    if (lane == 63) sa[256] = a4;
    __syncthreads();
    if (lane == 0) {
        const int lab = label_len[b];
        const float x = sa[2 * lab];
        const float y = sa[2 * lab - 1];
        out[b] = -lae2(x, y);
    }
}

extern "C" void kernel_launch(void* const* d_in, const int* in_sizes, int n_in,
                              void* d_out, int out_size, void* d_ws, size_t ws_size,
                              hipStream_t stream) {
    const int*   labels    = (const int*)d_in[0];   // true_labels   [B,L]
    const int*   label_len = (const int*)d_in[1];   // true_lengths  [B,1]
    const float* probs     = (const float*)d_in[2]; // predicted_labels [B,T,V]
    const int*   input_len = (const int*)d_in[3];   // predicted_lengths [B,1]
    float*       out       = (float*)d_out;         // [B,1]

    const int B = in_sizes[1];
    ctc_fwd_wave<<<B, 64, 0, stream>>>(labels, label_len, probs, input_len, out);
}

// Round 8
// 600.982 us; speedup vs baseline: 1.2304x; 1.0916x over previous
//
#include <hip/hip_runtime.h>

// CTC loss forward (R8 = R7 resubmit): producer/consumer wave specialization.
//
// R7's "container failed twice" was a broker/infra failure signature (no
// pytest traceback, unlike R4/R5's in-process aborts). The kernel design is
// within proven territory (135KB static LDS < 160KB gfx950 limit, m201
// precedent; uniform barriers only; aligned LDS). Resubmitting with minor
// hardening: producer loop unrolled 2x for deeper per-wave ILP.
//
// Theory (R1-R6 post-mortem): single-wave variants pin at ~950 cy/step =
// one memory round-trip per step -- the consume path always ends up behind
// an effective vmcnt(0) and one wave has no TLP. R8 decouples: wave 0 runs
// the recurrence touching ONLY LDS (nothing to drain); waves 1-7 gather
// log(p+EPS) of the 129 needed columns for the NEXT 128-step chunk into a
// double-buffered LDS table, HBM latency hidden by 7-wave TLP. 8 uniform
// barriers total. Math bit-identical to R6 (absmax 0).
//
// Shapes fixed: B=128, T=1024, V=512, L=128, S=257.
constexpr int Tc = 1024;
constexpr int Vc = 512;
constexpr int Lc = 128;
constexpr int Sc = 2 * Lc + 1;     // 257
constexpr int BLANK = Vc - 1;      // 511
constexpr float NEGF = -1e30f;
constexpr float EPSF = 1e-7f;
constexpr int CHUNK = 128;         // timesteps per chunk
constexpr int NCH = Tc / CHUNK;    // 8
constexpr int CCOLS = 132;         // padded row stride (floats)

__device__ __forceinline__ float lae2(float x, float y) {
    float m = fmaxf(x, y);
    return m + __logf(__expf(x - m) + __expf(y - m));
}
__device__ __forceinline__ float lae3(float x, float y, float z) {
    float m = fmaxf(fmaxf(x, y), z);
    return m + __logf(__expf(x - m) + __expf(y - m) + __expf(z - m));
}

__launch_bounds__(512, 1)
__global__ void ctc_fwd_pc(const int* __restrict__ labels,      // [B,L]
                           const int* __restrict__ label_len,   // [B,1]
                           const float* __restrict__ probs,     // [B,T,V]
                           const int* __restrict__ input_len,   // [B,1]
                           float* __restrict__ out)             // [B,1]
{
    const int b    = blockIdx.x;
    const int tid  = threadIdx.x;
    const int lane = tid & 63;
    const int wv   = tid >> 6;               // 0 = consumer, 1..7 = producers

    // cbuf[buf][r][k]: k<128 -> log p(labels[k]) at t=c*128+r; k==128 -> blank.
    __shared__ __align__(16) float cbuf[2][CHUNK][CCOLS];   // 135168 B
    __shared__ float sa[Sc];
    __shared__ int   slab[Lc];

    if (tid < Lc) slab[tid] = labels[b * Lc + tid];
    __syncthreads();

    const float* __restrict__ pb = probs + (size_t)b * Tc * Vc;

    // Producer: fill chunk c into cbuf[c&1]. Wave w owns rows r = w-1, w-1+7, ...
    // 2 scattered loads/lane/row (+ blank on lane 0); iterations independent;
    // unroll 2 keeps >=4 loads in flight per lane on top of 7-wave TLP.
    const int pc0 = slab[lane];              // label col for k=lane
    const int pc1 = slab[lane + 64];         // label col for k=lane+64
    auto fill = [&](int c) {
        const int t0 = c * CHUNK;
        float (* __restrict__ dst)[CCOLS] = cbuf[c & 1];
#pragma unroll 2
        for (int r = wv - 1; r < CHUNK; r += 7) {
            const float* __restrict__ prow = pb + (size_t)(t0 + r) * Vc;
            const float v0 = prow[pc0];
            const float v1 = prow[pc1];
            const float vb = (lane == 0) ? prow[BLANK] : 0.0f;
            dst[r][lane]      = __logf(v0 + EPSF);
            dst[r][lane + 64] = __logf(v1 + EPSF);
            if (lane == 0) dst[r][128] = __logf(vb + EPSF);
        }
    };

    // Consumer state (computed on all waves; used by wave 0 only).
    const int l0  = slab[2 * lane];
    const int l1  = slab[2 * lane + 1];
    const int lm1 = (lane > 0) ? slab[2 * lane - 1] : 0;
    const bool cs1 = (lane > 0) && (l0 != lm1);  // skip into state 4L+1
    const bool cs3 = (l1 != l0);                 // skip into state 4L+3
    const int len = input_len[b];
    const int lab = label_len[b];

    // alpha registers (time t-1 values); lane L owns states 4L..4L+3, lane 63 also 256.
    float a0 = (lane == 0) ? 0.0f : NEGF;
    float a1 = NEGF, a2 = NEGF, a3 = NEGF, a4 = NEGF;
    float u3 = NEGF;                             // prev-lane a3, pipelined one step

    if (wv != 0) fill(0);                        // prologue: chunk 0
    __syncthreads();

    for (int c = 0; c < NCH; ++c) {
        if (wv != 0) {
            if (c + 1 < NCH) fill(c + 1);        // fill buf[(c+1)&1] while wave 0 eats buf[c&1]
        } else {
            const float (* __restrict__ cb)[CCOLS] = cbuf[c & 1];
            // One-row register prefetch: read r+1 while computing r.
            float2 pv = *(const float2*)&cb[0][2 * lane];
            float  bv = cb[0][128];
            for (int r = 0; r < CHUNK; ++r) {
                float2 nv = pv; float nb = bv;
                if (r + 1 < CHUNK) {
                    nv = *(const float2*)&cb[r + 1][2 * lane];
                    nb = cb[r + 1][128];
                }
                const int t = c * CHUNK + r;
                const float lpb = bv;
                const float lp1 = pv.x;
                const float lp2 = pv.y;
                const float n3 = lae3(a3, a2, cs3 ? a1 : NEGF) + lp2;
                const float u3n = __shfl_up(n3, 1);
                const float n0 = lae2(a0, u3) + lpb;
                const float n1 = lae3(a1, a0, cs1 ? u3 : NEGF) + lp1;
                const float n2 = lae2(a2, a1) + lpb;
                const float n4 = lae2(a4, a3) + lpb;
                const bool live = (t < len);
                a0 = live ? n0 : a0;
                a1 = live ? n1 : a1;
                a2 = live ? n2 : a2;
                a3 = live ? n3 : a3;
                a4 = live ? n4 : a4;
                u3 = live ? ((lane == 0) ? NEGF : u3n) : u3;
                pv = nv; bv = nb;
            }
        }
        __syncthreads();                         // uniform: chunk handoff
    }

    // Gather final alphas and emit loss.
    if (wv == 0) {
        sa[4 * lane + 0] = a0;
        sa[4 * lane + 1] = a1;
        sa[4 * lane + 2] = a2;
        sa[4 * lane + 3] = a3;
        if (lane == 63) sa[256] = a4;
    }
    __syncthreads();
    if (tid == 0) {
        const float x = sa[2 * lab];
        const float y = sa[2 * lab - 1];
        out[b] = -lae2(x, y);
    }
}

extern "C" void kernel_launch(void* const* d_in, const int* in_sizes, int n_in,
                              void* d_out, int out_size, void* d_ws, size_t ws_size,
                              hipStream_t stream) {
    const int*   labels    = (const int*)d_in[0];   // true_labels   [B,L]
    const int*   label_len = (const int*)d_in[1];   // true_lengths  [B,1]
    const float* probs     = (const float*)d_in[2]; // predicted_labels [B,T,V]
    const int*   input_len = (const int*)d_in[3];   // predicted_lengths [B,1]
    float*       out       = (float*)d_out;         // [B,1]

    const int B = in_sizes[1];
    ctc_fwd_pc<<<B, 512, 0, stream>>>(labels, label_len, probs, input_len, out);
}